// Round 13
// baseline (157.191 us; speedup 1.0000x reference)
//
#include <hip/hip_runtime.h>
#include <hip/hip_bf16.h>
#include <stdint.h>

#define HIDDEN 1024
#define HEADS 16
#define HEAD_DIM 64
#define SEQ 4096
#define PATCH 4064
#define SKIP 32  // SEQ - PATCH

typedef __attribute__((ext_vector_type(8))) short bf16x8;
typedef __attribute__((ext_vector_type(4))) float f32x4;
typedef __attribute__((ext_vector_type(2))) float f32x2;
typedef __attribute__((ext_vector_type(16))) float f32x16;

__device__ __forceinline__ float b2f(unsigned short u){
  union{uint32_t i; float f;} c; c.i = ((uint32_t)u)<<16; return c.f;
}
__device__ __forceinline__ unsigned short f2b(float f){
  union{float f; uint32_t i;} c; c.f=f;
  uint32_t r = c.i + 0x7fffu + ((c.i>>16)&1u);
  return (unsigned short)(r>>16);
}
__device__ __forceinline__ uint32_t cvtpk(float a, float b){
  uint32_t r;
  asm("v_cvt_pk_bf16_f32 %0, %1, %2" : "=v"(r) : "v"(a), "v"(b));
  return r;
}

#define GLD16(gp, lp) __builtin_amdgcn_global_load_lds( \
    (const __attribute__((address_space(1))) void*)(gp), \
    (__attribute__((address_space(3))) void*)(lp), 16, 0, 0)

// ---------------- fp32 -> bf16 conversion (x + 4 weights) ----------------
__global__ __launch_bounds__(256) void convert_all(
    const float* __restrict__ x,  const float* __restrict__ wq,
    const float* __restrict__ wk, const float* __restrict__ wv,
    const float* __restrict__ wo,
    unsigned short* __restrict__ xb,  unsigned short* __restrict__ wqb,
    unsigned short* __restrict__ wkb, unsigned short* __restrict__ wvb,
    unsigned short* __restrict__ wob)
{
  size_t u = (size_t)blockIdx.x*256 + threadIdx.x;
  size_t e = u*8;
  const float* src; unsigned short* dst; size_t off;
  if      (e < 4194304ull) { src=x;  dst=xb;  off=e;            }
  else if (e < 5242880ull) { src=wq; dst=wqb; off=e-4194304ull; }
  else if (e < 6291456ull) { src=wk; dst=wkb; off=e-5242880ull; }
  else if (e < 7340032ull) { src=wv; dst=wvb; off=e-6291456ull; }
  else                     { src=wo; dst=wob; off=e-7340032ull; }
  float4 v0 = *(const float4*)(src+off);
  float4 v1 = *(const float4*)(src+off+4);
  union { bf16x8 v; unsigned short h[8]; } o;
  o.h[0]=f2b(v0.x); o.h[1]=f2b(v0.y); o.h[2]=f2b(v0.z); o.h[3]=f2b(v0.w);
  o.h[4]=f2b(v1.x); o.h[5]=f2b(v1.y); o.h[6]=f2b(v1.z); o.h[7]=f2b(v1.w);
  *(bf16x8*)(dst+off) = o.v;
}

// ---------------- QKV GEMM: 128x128 tile, dbuf + prefetch, fused RMS+RoPE ----------------
// XCD-swizzled block remap: same-XCD blocks share 3 weight panels in their L2.
// sel 0/1 -> RMS-norm + RoPE -> q/k bf16.
// sel 2   -> V transposed in-epilogue to vt[h][d][s'] (s' = kv bits 2<->3 swapped).
__global__ __launch_bounds__(256) void gemm_qkv(
    const unsigned short* __restrict__ A,
    const unsigned short* __restrict__ B0,
    const unsigned short* __restrict__ B1,
    const unsigned short* __restrict__ B2,
    unsigned short* __restrict__ qout, unsigned short* __restrict__ kout,
    unsigned short* __restrict__ vtout,
    const float* __restrict__ rc, const float* __restrict__ rs,
    const float* __restrict__ qw, const float* __restrict__ kw,
    int M, int Nper, int K)
{
  __shared__ unsigned short smem[16896];  // 33792B: 32KB staging + transpose headroom
  const int tid = threadIdx.x;
  const int w = tid>>6, l = tid&63;
  const int wm = w>>1, wn = w&1;
  const int g = l>>4, lr = l&15;
  // XCD-aware remap: orig%8 = XCD; give each XCD a contiguous wg chunk (768%8==0)
  const int orig = blockIdx.x + 32*blockIdx.y;
  const int wg = (orig&7)*96 + (orig>>3);
  const int bm = wg & 31;
  int bn = wg >> 5;                       // [0,24)
  const int tilesPer = Nper >> 7;
  const int sel = bn / tilesPer;
  bn -= sel*tilesPer;
  const unsigned short* Bsel = (sel==0) ? B0 : ((sel==1) ? B1 : B2);

  const int off0 = w*1024 + l*16;       // [0,4096) bytes
  const int r0 = off0>>6, c0 = (off0&63)>>1;
  const int off1 = off0 + 4096;         // [4096,8192)
  const int r1 = off1>>6, c1 = (off1&63)>>1;

  const unsigned short* Ab = A    + (size_t)(bm*128)*K;
  const unsigned short* Bb = Bsel + (size_t)(bn*128)*K;

#define STG(db, kt) do { \
    GLD16(Ab + (size_t)r0*K + (kt) + c0, (char*)smem + (db) + off0); \
    GLD16(Ab + (size_t)r1*K + (kt) + c1, (char*)smem + (db) + off1); \
    GLD16(Bb + (size_t)r0*K + (kt) + c0, (char*)smem + (db) + 8192 + off0); \
    GLD16(Bb + (size_t)r1*K + (kt) + c1, (char*)smem + (db) + 8192 + off1); } while(0)

  f32x4 zero = {0.f,0.f,0.f,0.f};
  f32x4 acc[4][4];
  #pragma unroll
  for (int m=0;m<4;m++)
    #pragma unroll
    for (int n=0;n<4;n++) acc[m][n]=zero;

  const int nkt = K >> 5;
  STG(0, 0);
  for (int t = 0; t < nkt; ++t) {
    __syncthreads();
    const int db = (t&1)<<14;
    if (t+1 < nkt) STG(db^16384, (t+1)*32);
    bf16x8 a[4], b[4];
    #pragma unroll
    for (int m=0;m<4;m++)
      a[m] = *(const bf16x8*)((char*)smem + db + (wm*64 + m*16 + lr)*64 + g*16);
    #pragma unroll
    for (int n=0;n<4;n++)
      b[n] = *(const bf16x8*)((char*)smem + db + 8192 + (wn*64 + n*16 + lr)*64 + g*16);
    #pragma unroll
    for (int m=0;m<4;m++)
      #pragma unroll
      for (int n=0;n<4;n++)
        acc[m][n] = __builtin_amdgcn_mfma_f32_16x16x32_bf16(a[m], b[n], acc[m][n], 0,0,0);
  }
#undef STG

  if (sel <= 1) {
    // fused RMS-norm + RoPE; wave's 64-col span == one head
    const float* nw = (sel==0) ? qw : kw;
    unsigned short* dst = (sel==0) ? qout : kout;
    const float scl = (sel==0) ? 0.18033688011112042f : 1.0f;  // 0.125*log2(e)
    float wl[4];
    #pragma unroll
    for (int n=0;n<4;n++) wl[n] = nw[n*16+lr];
    const int hglob = bn*2 + wn;
    #pragma unroll
    for (int m=0;m<4;m++){
      const int rowb = bm*128 + wm*64 + m*16 + g*4;
      float rn[4];
      #pragma unroll
      for (int r=0;r<4;r++){
        float ss = 0.f;
        #pragma unroll
        for (int n=0;n<4;n++) ss += acc[m][n][r]*acc[m][n][r];
        ss += __shfl_xor(ss,1); ss += __shfl_xor(ss,2);
        ss += __shfl_xor(ss,4); ss += __shfl_xor(ss,8);
        rn[r] = rsqrtf(ss*(1.f/64.f) + 1e-6f);
      }
      #pragma unroll
      for (int r=0;r<4;r++){
        const int row = rowb + r;
        const int p = row - SKIP;
        #pragma unroll
        for (int n=0;n<4;n++){
          float v = acc[m][n][r]*rn[r]*wl[n];
          float c = 1.f, sn = 0.f;
          if (p >= 0){
            const int d2 = (n*16+lr)>>1;
            c  = rc[p*(HEAD_DIM/2) + d2];
            sn = rs[p*(HEAD_DIM/2) + d2];
          }
          const float partner = __shfl_xor(v, 1);
          const float o2 = (lr&1) ? (partner*sn + v*c) : (v*c - partner*sn);
          dst[(size_t)row*HIDDEN + hglob*64 + n*16 + lr] = f2b(o2*scl);
        }
      }
    }
  } else {
    // V: per-wave LDS transpose -> vt[h][d][s'] with kv bit2<->3 swap.
    const int hglob = bn*2 + wn;
    const int sbase = bm*128 + wm*64;
    unsigned short* lchunk = smem + w*4224;   // 64 x 66 shorts per wave
    __syncthreads();
    #pragma unroll
    for (int m=0;m<4;m++)
      #pragma unroll
      for (int n=0;n<4;n++)
        #pragma unroll
        for (int r=0;r<4;r++)
          lchunk[(m*16 + g*4 + r)*66 + n*16 + lr] = f2b(acc[m][n][r]);
    __syncthreads();
    #pragma unroll
    for (int i=0;i<8;i++){
      const int e = i*64 + l;
      const int d = e>>3, sc = (e&7)*8;
      union { bf16x8 v8; unsigned short h8[8]; } o;
      #pragma unroll
      for (int j=0;j<8;j++){
        const int x  = sc + j;
        const int px = (x & ~12) | ((x&4)<<1) | ((x&8)>>1);  // swap bits 2,3
        o.h8[j] = lchunk[px*66 + d];
      }
      *(bf16x8*)(vtout + (size_t)(hglob*HEAD_DIM + d)*SEQ + sbase + sc) = o.v8;
    }
  }
}

// ---------------- out-proj GEMM: 128x64 tile, XCD-swizzled, grid 512 ----------------
__global__ __launch_bounds__(256) void gemm_out(
    const unsigned short* __restrict__ A,
    const unsigned short* __restrict__ B,
    float* __restrict__ Cf, int M, int N, int K)
{
  __shared__ unsigned short smem[12288];  // 24KB: 2 bufs x (A 8KB + B 4KB)
  const int tid = threadIdx.x;
  const int w = tid>>6, l = tid&63;
  const int wm = w>>1, wn = w&1;
  const int g = l>>4, lr = l&15;
  const int orig = blockIdx.x + 32*blockIdx.y;   // [0,512)
  const int wg = (orig&7)*64 + (orig>>3);
  const int bm = wg & 31;
  const int bn = wg >> 5;   // [0,16)

  const int off0 = w*1024 + l*16;
  const int r0 = off0>>6, c0 = (off0&63)>>1;
  const int off1 = off0 + 4096;
  const int r1 = off1>>6, c1 = (off1&63)>>1;
  const int offB = tid*16;              // [0,4096) — B tile 64 rows x 64B
  const int rB = offB>>6, cB = (offB&63)>>1;

  const unsigned short* Ab = A + (size_t)(bm*128)*K;
  const unsigned short* Bb = B + (size_t)(bn*64)*K;

#define STG(db, kt) do { \
    GLD16(Ab + (size_t)r0*K + (kt) + c0, (char*)smem + (db) + off0); \
    GLD16(Ab + (size_t)r1*K + (kt) + c1, (char*)smem + (db) + off1); \
    GLD16(Bb + (size_t)rB*K + (kt) + cB, (char*)smem + (db) + 8192 + offB); } while(0)

  f32x4 zero = {0.f,0.f,0.f,0.f};
  f32x4 acc[4][2];
  #pragma unroll
  for (int m=0;m<4;m++)
    #pragma unroll
    for (int n=0;n<2;n++) acc[m][n]=zero;

  const int nkt = K >> 5;
  STG(0, 0);
  for (int t = 0; t < nkt; ++t) {
    __syncthreads();
    const int db = (t&1)*12288;
    if (t+1 < nkt) STG(db^12288, (t+1)*32);
    bf16x8 a[4], b[2];
    #pragma unroll
    for (int m=0;m<4;m++)
      a[m] = *(const bf16x8*)((char*)smem + db + (wm*64 + m*16 + lr)*64 + g*16);
    #pragma unroll
    for (int n=0;n<2;n++)
      b[n] = *(const bf16x8*)((char*)smem + db + 8192 + (wn*32 + n*16 + lr)*64 + g*16);
    #pragma unroll
    for (int m=0;m<4;m++)
      #pragma unroll
      for (int n=0;n<2;n++)
        acc[m][n] = __builtin_amdgcn_mfma_f32_16x16x32_bf16(a[m], b[n], acc[m][n], 0,0,0);
  }
#undef STG

  #pragma unroll
  for (int m=0;m<4;m++){
    const int row = bm*128 + wm*64 + m*16 + g*4;
    #pragma unroll
    for (int n=0;n<2;n++){
      const int col = bn*64 + wn*32 + n*16 + lr;
      #pragma unroll
      for (int r=0;r<4;r++)
        Cf[(size_t)(row+r)*N + col] = acc[m][n][r];
    }
  }
}

__device__ __forceinline__ void softmax_pack(f32x16 (&st)[2], f32x2 &lacc, bf16x8 (&pf)[4]){
  float pv[32];
  #pragma unroll
  for (int i=0;i<16;i++){
    pv[i]    = __builtin_amdgcn_exp2f(st[0][i]);
    pv[16+i] = __builtin_amdgcn_exp2f(st[1][i]);
  }
  #pragma unroll
  for (int i=0;i<8;i++){
    f32x2 a; a.x = pv[2*i];    a.y = pv[2*i+1];    lacc += a;
    f32x2 b; b.x = pv[16+2*i]; b.y = pv[16+2*i+1]; lacc += b;
  }
  #pragma unroll
  for (int t2=0; t2<2; t2++)
    #pragma unroll
    for (int e=0; e<2; e++){
      union { uint32_t u4[4]; bf16x8 v8; } pu;
      #pragma unroll
      for (int u=0; u<4; u++)
        pu.u4[u] = cvtpk(pv[t2*16+e*8+2*u], pv[t2*16+e*8+2*u+1]);
      pf[2*t2+e] = pu.v8;
    }
}

// ---------------- flash attention: 512 thr, 2 kv-halves x 4 waves, KVBLK=128 ----------------
// KVBLK=128 per half (16 barriers instead of 32 — r7-proven staging); in-block
// LDS merge epilogue: at = (O0+O1)/(l0+l1). LDS 133KB, 1 block/CU (grid-limited).
__global__ __launch_bounds__(512, 1) void attn_kernel(
    const unsigned short* __restrict__ q, const unsigned short* __restrict__ k,
    const unsigned short* __restrict__ vt, unsigned short* __restrict__ at)
{
  __shared__ unsigned short smem[65536];  // 128KB: [half][2 dbuf][K 16KB | V 16KB]
  __shared__ float lsm[512];              // [half][256] row sums
  const int fid = blockIdx.x + 16*blockIdx.y;   // [0,256)
  const int h  = (fid&7)*2 + ((fid>>3)&1);      // XCD-grouped heads
  const int q0 = (fid>>4)*256;
  const int tid = threadIdx.x;
  const int half = tid>>8;                // 0/1: kv half
  const int ht = tid&255;                 // thread within half
  const int w = (tid>>6)&3, l = tid&63;   // wave within half, lane
  const int hi = l>>5, lo = l&31;
  const int NT = 16;                      // tiles of 128 kv per half
  const int tbase = half*NT;
  const int hbase = half*65536;           // byte offset of half's LDS region

  // ---- staging: 4 K-chunks + 4 V-chunks per thread (16B each), KVBLK=128 ----
  // K tile [128 kv][128B] = 16KB; V tile [64 d][256B] (two swizzled 128B halves)
  const unsigned short* kPtr[4]; const unsigned short* vPtr[4];
  #pragma unroll
  for (int i=0;i<4;i++){
    const int c = ht + i*256;
    const int rk = c>>3;
    const int kcol = ((c&7)*16) ^ ((rk&7)<<4);
    const int rv = c>>4;
    const int vcol = (((c&7)*16) ^ ((rv&7)<<4)) + ((c>>3)&1)*128;
    kPtr[i] = k  + (size_t)rk*HIDDEN + h*HEAD_DIM + (kcol>>1);
    vPtr[i] = vt + ((size_t)(h*HEAD_DIM + rv))*SEQ + (vcol>>1);
  }

#define STAGE(b, kOffE, vOffE) do { \
    GLD16(kPtr[0] + (kOffE), (char*)smem + hbase + (b)*32768 + (ht      )*16); \
    GLD16(kPtr[1] + (kOffE), (char*)smem + hbase + (b)*32768 + (ht+ 256 )*16); \
    GLD16(kPtr[2] + (kOffE), (char*)smem + hbase + (b)*32768 + (ht+ 512 )*16); \
    GLD16(kPtr[3] + (kOffE), (char*)smem + hbase + (b)*32768 + (ht+ 768 )*16); \
    GLD16(vPtr[0] + (vOffE), (char*)smem + hbase + (b)*32768 + 16384 + (ht      )*16); \
    GLD16(vPtr[1] + (vOffE), (char*)smem + hbase + (b)*32768 + 16384 + (ht+ 256 )*16); \
    GLD16(vPtr[2] + (vOffE), (char*)smem + hbase + (b)*32768 + 16384 + (ht+ 512 )*16); \
    GLD16(vPtr[3] + (vOffE), (char*)smem + hbase + (b)*32768 + 16384 + (ht+ 768 )*16); \
  } while(0)

  const int swz = (lo&7)<<4;
  int colo[4];
  #pragma unroll
  for (int ks=0; ks<4; ks++) colo[ks] = ((2*ks+hi)*16) ^ swz;

  bf16x8 qf0[4], qf1[4];
  {
    const unsigned short* qp = q + (size_t)(q0 + w*64 + lo)*HIDDEN + h*HEAD_DIM;
    #pragma unroll
    for (int ks=0; ks<4; ks++){
      qf0[ks] = *(const bf16x8*)(qp + ks*16 + hi*8);
      qf1[ks] = *(const bf16x8*)(qp + 32*HIDDEN + ks*16 + hi*8);
    }
  }

  f32x16 ot0[2], ot1[2];
  #pragma unroll
  for (int m2=0;m2<2;m2++)
    #pragma unroll
    for (int i=0;i<16;i++){ ot0[m2][i] = 0.f; ot1[m2][i] = 0.f; }
  f32x2 lacc0 = {0.f,0.f}, lacc1 = {0.f,0.f};

  STAGE(0, (size_t)tbase*128*HIDDEN, (size_t)tbase*128);

  for (int t = 0; t < NT; ++t) {
    __syncthreads();
    if (t+1 < NT) {
      const size_t ta = (size_t)(tbase + t + 1);
      STAGE((t+1)&1, ta*128*HIDDEN, ta*128);
    }
    const char* Kb = (const char*)smem + hbase + (t&1)*32768;
    const char* Vb = Kb + 16384;

    #pragma unroll
    for (int sub=0; sub<2; ++sub) {
      const char* Ks = Kb + sub*8192;      // 64 kv rows of 128B

      f32x16 st0[2], st1[2];
      __builtin_amdgcn_s_setprio(1);
      #pragma unroll
      for (int c=0;c<2;c++){
        #pragma unroll
        for (int i=0;i<16;i++){ st0[c][i] = 0.f; st1[c][i] = 0.f; }
        #pragma unroll
        for (int ks=0; ks<4; ks++){
          bf16x8 a = *(const bf16x8*)(Ks + (32*c+lo)*128 + colo[ks]);
          st0[c] = __builtin_amdgcn_mfma_f32_32x32x16_bf16(a, qf0[ks], st0[c], 0,0,0);
          st1[c] = __builtin_amdgcn_mfma_f32_32x32x16_bf16(a, qf1[ks], st1[c], 0,0,0);
        }
      }
      __builtin_amdgcn_s_setprio(0);

      bf16x8 pf0[4], pf1[4];
      softmax_pack(st0, lacc0, pf0);
      softmax_pack(st1, lacc1, pf1);

      __builtin_amdgcn_s_setprio(1);
      #pragma unroll
      for (int m2=0;m2<2;m2++)
        #pragma unroll
        for (int ks=0; ks<4; ks++){
          bf16x8 a = *(const bf16x8*)(Vb + (32*m2+lo)*256 + sub*128 + colo[ks]);
          ot0[m2] = __builtin_amdgcn_mfma_f32_32x32x16_bf16(a, pf0[ks], ot0[m2], 0,0,0);
          ot1[m2] = __builtin_amdgcn_mfma_f32_32x32x16_bf16(a, pf1[ks], ot1[m2], 0,0,0);
        }
      __builtin_amdgcn_s_setprio(0);
    }
  }

  // ---- per-lane row sums ----
  float ls0 = lacc0.x + lacc0.y;
  ls0 += __shfl_xor(ls0, 32);
  float ls1 = lacc1.x + lacc1.y;
  ls1 += __shfl_xor(ls1, 32);

  __syncthreads();   // all waves done reading staging LDS
  if (hi == 0){
    lsm[half*256 + w*64 + lo]      = ls0;
    lsm[half*256 + w*64 + 32 + lo] = ls1;
  }
  // ---- O fragments -> own half's LDS region ([256 q][128B], swizzled rows) ----
  #pragma unroll
  for (int m2=0;m2<2;m2++)
    #pragma unroll
    for (int f=0; f<4; f++)
      #pragma unroll
      for (int u=0; u<2; u++){
        const int d = 32*m2 + 8*f + 4*hi + 2*u;
        const uint32_t w0 = cvtpk(ot0[m2][4*f+2*u], ot0[m2][4*f+2*u+1]);
        *(uint32_t*)((char*)smem + hbase + (w*64+lo)*128 + ((d*2) ^ swz)) = w0;
        const uint32_t w1 = cvtpk(ot1[m2][4*f+2*u], ot1[m2][4*f+2*u+1]);
        *(uint32_t*)((char*)smem + hbase + (w*64+32+lo)*128 + ((d*2) ^ swz)) = w1;
      }
  __syncthreads();

  // ---- merge halves + normalize + coalesced write: 512 thr x 4 chunks ----
  {
    const int ql = tid>>1, xh = tid&1;
    const float li = 1.0f / (lsm[ql] + lsm[256 + ql]);
    #pragma unroll
    for (int i=0;i<4;i++){
      const int cb = xh*64 + i*16;
      const int off = ql*128 + (cb ^ ((ql&7)<<4));
      union { bf16x8 v; unsigned short s[8]; } a, b, o;
      a.v = *(const bf16x8*)((const char*)smem + off);
      b.v = *(const bf16x8*)((const char*)smem + 65536 + off);
      #pragma unroll
      for (int j=0;j<8;j++)
        o.s[j] = f2b((b2f(a.s[j]) + b2f(b.s[j])) * li);
      *(bf16x8*)(at + (size_t)(q0+ql)*HIDDEN + h*HEAD_DIM + (cb>>1)) = o.v;
    }
  }
#undef STAGE
}

extern "C" void kernel_launch(void* const* d_in, const int* in_sizes, int n_in,
                              void* d_out, int out_size, void* d_ws, size_t ws_size,
                              hipStream_t stream)
{
  const float* x  = (const float*)d_in[0];
  const float* rc = (const float*)d_in[1];
  const float* rs = (const float*)d_in[2];
  const float* wq = (const float*)d_in[3];
  const float* wk = (const float*)d_in[4];
  const float* wv = (const float*)d_in[5];
  const float* wo = (const float*)d_in[6];
  const float* qw = (const float*)d_in[7];
  const float* kw = (const float*)d_in[8];
  float* out = (float*)d_out;

  char* ws = (char*)d_ws;
  const size_t MB = 1024*1024;
  // layout (48MB):
  //  0.. 8: xb (A input, live through gemm_qkv)
  //  8..10 wqb  10..12 wkb  12..14 wvb (dead after qkv gemm)  14..16: wob (live)
  // 16..24 q, 24..32 k
  // 32..40: vt (written directly by gemm_qkv sel=2 epilogue)
  // 40..48: at (attention output, written directly by attn_kernel)
  unsigned short* xb  = (unsigned short*)(ws + 0);
  unsigned short* wqb = (unsigned short*)(ws + 8*MB);
  unsigned short* wkb = (unsigned short*)(ws + 10*MB);
  unsigned short* wvb = (unsigned short*)(ws + 12*MB);
  unsigned short* wob = (unsigned short*)(ws + 14*MB);
  unsigned short* qkv = (unsigned short*)(ws + 16*MB);
  unsigned short* qb = qkv;
  unsigned short* kb = qkv + (size_t)SEQ*HIDDEN;
  unsigned short* vt = (unsigned short*)(ws + 32*MB);
  unsigned short* at = (unsigned short*)(ws + 40*MB);

  convert_all<<<4096, 256, 0, stream>>>(x, wq, wk, wv, wo, xb, wqb, wkb, wvb, wob);
  gemm_qkv<<<dim3(32,24), 256, 0, stream>>>(
      xb, wqb, wkb, wvb, qb, kb, vt, rc, rs, qw, kw, SEQ, HIDDEN, HIDDEN);
  attn_kernel<<<dim3(16,16), 512, 0, stream>>>(qb, kb, vt, at);
  gemm_out<<<dim3(32,16), 256, 0, stream>>>(at, wob, out, SEQ, HIDDEN, HIDDEN);
}

// Round 14
// 147.785 us; speedup vs baseline: 1.0636x; 1.0636x over previous
//
#include <hip/hip_runtime.h>
#include <hip/hip_bf16.h>
#include <stdint.h>

#define HIDDEN 1024
#define HEADS 16
#define HEAD_DIM 64
#define SEQ 4096
#define PATCH 4064
#define SKIP 32  // SEQ - PATCH

typedef __attribute__((ext_vector_type(8))) short bf16x8;
typedef __attribute__((ext_vector_type(4))) float f32x4;
typedef __attribute__((ext_vector_type(2))) float f32x2;
typedef __attribute__((ext_vector_type(16))) float f32x16;

__device__ __forceinline__ float b2f(unsigned short u){
  union{uint32_t i; float f;} c; c.i = ((uint32_t)u)<<16; return c.f;
}
__device__ __forceinline__ unsigned short f2b(float f){
  union{float f; uint32_t i;} c; c.f=f;
  uint32_t r = c.i + 0x7fffu + ((c.i>>16)&1u);
  return (unsigned short)(r>>16);
}
__device__ __forceinline__ uint32_t cvtpk(float a, float b){
  uint32_t r;
  asm("v_cvt_pk_bf16_f32 %0, %1, %2" : "=v"(r) : "v"(a), "v"(b));
  return r;
}

#define GLD16(gp, lp) __builtin_amdgcn_global_load_lds( \
    (const __attribute__((address_space(1))) void*)(gp), \
    (__attribute__((address_space(3))) void*)(lp), 16, 0, 0)

// ---------------- fp32 -> bf16 conversion (x + 4 weights) ----------------
__global__ __launch_bounds__(256) void convert_all(
    const float* __restrict__ x,  const float* __restrict__ wq,
    const float* __restrict__ wk, const float* __restrict__ wv,
    const float* __restrict__ wo,
    unsigned short* __restrict__ xb,  unsigned short* __restrict__ wqb,
    unsigned short* __restrict__ wkb, unsigned short* __restrict__ wvb,
    unsigned short* __restrict__ wob)
{
  size_t u = (size_t)blockIdx.x*256 + threadIdx.x;
  size_t e = u*8;
  const float* src; unsigned short* dst; size_t off;
  if      (e < 4194304ull) { src=x;  dst=xb;  off=e;            }
  else if (e < 5242880ull) { src=wq; dst=wqb; off=e-4194304ull; }
  else if (e < 6291456ull) { src=wk; dst=wkb; off=e-5242880ull; }
  else if (e < 7340032ull) { src=wv; dst=wvb; off=e-6291456ull; }
  else                     { src=wo; dst=wob; off=e-7340032ull; }
  float4 v0 = *(const float4*)(src+off);
  float4 v1 = *(const float4*)(src+off+4);
  union { bf16x8 v; unsigned short h[8]; } o;
  o.h[0]=f2b(v0.x); o.h[1]=f2b(v0.y); o.h[2]=f2b(v0.z); o.h[3]=f2b(v0.w);
  o.h[4]=f2b(v1.x); o.h[5]=f2b(v1.y); o.h[6]=f2b(v1.z); o.h[7]=f2b(v1.w);
  *(bf16x8*)(dst+off) = o.v;
}

// ---------------- QKV GEMM: 128x128 tile, dbuf + prefetch, fused RMS+RoPE ----------------
// Natural block mapping (r13 lesson: XCD remap broke A-panel L2 locality, −13µs).
// sel 0/1 -> RMS-norm + RoPE -> q/k bf16.
// sel 2   -> V transposed in-epilogue to vt[h][d][s'] (s' = kv bits 2<->3 swapped).
__global__ __launch_bounds__(256) void gemm_qkv(
    const unsigned short* __restrict__ A,
    const unsigned short* __restrict__ B0,
    const unsigned short* __restrict__ B1,
    const unsigned short* __restrict__ B2,
    unsigned short* __restrict__ qout, unsigned short* __restrict__ kout,
    unsigned short* __restrict__ vtout,
    const float* __restrict__ rc, const float* __restrict__ rs,
    const float* __restrict__ qw, const float* __restrict__ kw,
    int M, int Nper, int K)
{
  __shared__ unsigned short smem[16896];  // 33792B: 32KB staging + transpose headroom
  const int tid = threadIdx.x;
  const int w = tid>>6, l = tid&63;
  const int wm = w>>1, wn = w&1;
  const int g = l>>4, lr = l&15;
  const int bm = blockIdx.x;
  int bn = blockIdx.y;
  const int tilesPer = Nper >> 7;
  const int sel = bn / tilesPer;
  bn -= sel*tilesPer;
  const unsigned short* Bsel = (sel==0) ? B0 : ((sel==1) ? B1 : B2);

  const int off0 = w*1024 + l*16;       // [0,4096) bytes
  const int r0 = off0>>6, c0 = (off0&63)>>1;
  const int off1 = off0 + 4096;         // [4096,8192)
  const int r1 = off1>>6, c1 = (off1&63)>>1;

  const unsigned short* Ab = A    + (size_t)(bm*128)*K;
  const unsigned short* Bb = Bsel + (size_t)(bn*128)*K;

#define STG(db, kt) do { \
    GLD16(Ab + (size_t)r0*K + (kt) + c0, (char*)smem + (db) + off0); \
    GLD16(Ab + (size_t)r1*K + (kt) + c1, (char*)smem + (db) + off1); \
    GLD16(Bb + (size_t)r0*K + (kt) + c0, (char*)smem + (db) + 8192 + off0); \
    GLD16(Bb + (size_t)r1*K + (kt) + c1, (char*)smem + (db) + 8192 + off1); } while(0)

  f32x4 zero = {0.f,0.f,0.f,0.f};
  f32x4 acc[4][4];
  #pragma unroll
  for (int m=0;m<4;m++)
    #pragma unroll
    for (int n=0;n<4;n++) acc[m][n]=zero;

  const int nkt = K >> 5;
  STG(0, 0);
  for (int t = 0; t < nkt; ++t) {
    __syncthreads();
    const int db = (t&1)<<14;
    if (t+1 < nkt) STG(db^16384, (t+1)*32);
    bf16x8 a[4], b[4];
    #pragma unroll
    for (int m=0;m<4;m++)
      a[m] = *(const bf16x8*)((char*)smem + db + (wm*64 + m*16 + lr)*64 + g*16);
    #pragma unroll
    for (int n=0;n<4;n++)
      b[n] = *(const bf16x8*)((char*)smem + db + 8192 + (wn*64 + n*16 + lr)*64 + g*16);
    #pragma unroll
    for (int m=0;m<4;m++)
      #pragma unroll
      for (int n=0;n<4;n++)
        acc[m][n] = __builtin_amdgcn_mfma_f32_16x16x32_bf16(a[m], b[n], acc[m][n], 0,0,0);
  }
#undef STG

  if (sel <= 1) {
    // fused RMS-norm + RoPE; wave's 64-col span == one head
    const float* nw = (sel==0) ? qw : kw;
    unsigned short* dst = (sel==0) ? qout : kout;
    const float scl = (sel==0) ? 0.18033688011112042f : 1.0f;  // 0.125*log2(e)
    float wl[4];
    #pragma unroll
    for (int n=0;n<4;n++) wl[n] = nw[n*16+lr];
    const int hglob = bn*2 + wn;
    #pragma unroll
    for (int m=0;m<4;m++){
      const int rowb = bm*128 + wm*64 + m*16 + g*4;
      float rn[4];
      #pragma unroll
      for (int r=0;r<4;r++){
        float ss = 0.f;
        #pragma unroll
        for (int n=0;n<4;n++) ss += acc[m][n][r]*acc[m][n][r];
        ss += __shfl_xor(ss,1); ss += __shfl_xor(ss,2);
        ss += __shfl_xor(ss,4); ss += __shfl_xor(ss,8);
        rn[r] = rsqrtf(ss*(1.f/64.f) + 1e-6f);
      }
      #pragma unroll
      for (int r=0;r<4;r++){
        const int row = rowb + r;
        const int p = row - SKIP;
        #pragma unroll
        for (int n=0;n<4;n++){
          float v = acc[m][n][r]*rn[r]*wl[n];
          float c = 1.f, sn = 0.f;
          if (p >= 0){
            const int d2 = (n*16+lr)>>1;
            c  = rc[p*(HEAD_DIM/2) + d2];
            sn = rs[p*(HEAD_DIM/2) + d2];
          }
          const float partner = __shfl_xor(v, 1);
          const float o2 = (lr&1) ? (partner*sn + v*c) : (v*c - partner*sn);
          dst[(size_t)row*HIDDEN + hglob*64 + n*16 + lr] = f2b(o2*scl);
        }
      }
    }
  } else {
    // V: per-wave LDS transpose -> vt[h][d][s'] with kv bit2<->3 swap.
    const int hglob = bn*2 + wn;
    const int sbase = bm*128 + wm*64;
    unsigned short* lchunk = smem + w*4224;   // 64 x 66 shorts per wave
    __syncthreads();
    #pragma unroll
    for (int m=0;m<4;m++)
      #pragma unroll
      for (int n=0;n<4;n++)
        #pragma unroll
        for (int r=0;r<4;r++)
          lchunk[(m*16 + g*4 + r)*66 + n*16 + lr] = f2b(acc[m][n][r]);
    __syncthreads();
    #pragma unroll
    for (int i=0;i<8;i++){
      const int e = i*64 + l;
      const int d = e>>3, sc = (e&7)*8;
      union { bf16x8 v8; unsigned short h8[8]; } o;
      #pragma unroll
      for (int j=0;j<8;j++){
        const int x  = sc + j;
        const int px = (x & ~12) | ((x&4)<<1) | ((x&8)>>1);  // swap bits 2,3
        o.h8[j] = lchunk[px*66 + d];
      }
      *(bf16x8*)(vtout + (size_t)(hglob*HEAD_DIM + d)*SEQ + sbase + sc) = o.v8;
    }
  }
}

// ---------------- out-proj GEMM: 128x64 tile, natural mapping, grid 512 ----------------
__global__ __launch_bounds__(256) void gemm_out(
    const unsigned short* __restrict__ A,
    const unsigned short* __restrict__ B,
    float* __restrict__ Cf, int M, int N, int K)
{
  __shared__ unsigned short smem[12288];  // 24KB: 2 bufs x (A 8KB + B 4KB)
  const int tid = threadIdx.x;
  const int w = tid>>6, l = tid&63;
  const int wm = w>>1, wn = w&1;
  const int g = l>>4, lr = l&15;
  const int bm = blockIdx.x;   // 0..31
  const int bn = blockIdx.y;   // 0..15

  const int off0 = w*1024 + l*16;
  const int r0 = off0>>6, c0 = (off0&63)>>1;
  const int off1 = off0 + 4096;
  const int r1 = off1>>6, c1 = (off1&63)>>1;
  const int offB = tid*16;              // [0,4096) — B tile 64 rows x 64B
  const int rB = offB>>6, cB = (offB&63)>>1;

  const unsigned short* Ab = A + (size_t)(bm*128)*K;
  const unsigned short* Bb = B + (size_t)(bn*64)*K;

#define STG(db, kt) do { \
    GLD16(Ab + (size_t)r0*K + (kt) + c0, (char*)smem + (db) + off0); \
    GLD16(Ab + (size_t)r1*K + (kt) + c1, (char*)smem + (db) + off1); \
    GLD16(Bb + (size_t)rB*K + (kt) + cB, (char*)smem + (db) + 8192 + offB); } while(0)

  f32x4 zero = {0.f,0.f,0.f,0.f};
  f32x4 acc[4][2];
  #pragma unroll
  for (int m=0;m<4;m++)
    #pragma unroll
    for (int n=0;n<2;n++) acc[m][n]=zero;

  const int nkt = K >> 5;
  STG(0, 0);
  for (int t = 0; t < nkt; ++t) {
    __syncthreads();
    const int db = (t&1)*12288;
    if (t+1 < nkt) STG(db^12288, (t+1)*32);
    bf16x8 a[4], b[2];
    #pragma unroll
    for (int m=0;m<4;m++)
      a[m] = *(const bf16x8*)((char*)smem + db + (wm*64 + m*16 + lr)*64 + g*16);
    #pragma unroll
    for (int n=0;n<2;n++)
      b[n] = *(const bf16x8*)((char*)smem + db + 8192 + (wn*32 + n*16 + lr)*64 + g*16);
    #pragma unroll
    for (int m=0;m<4;m++)
      #pragma unroll
      for (int n=0;n<2;n++)
        acc[m][n] = __builtin_amdgcn_mfma_f32_16x16x32_bf16(a[m], b[n], acc[m][n], 0,0,0);
  }
#undef STG

  #pragma unroll
  for (int m=0;m<4;m++){
    const int row = bm*128 + wm*64 + m*16 + g*4;
    #pragma unroll
    for (int n=0;n<2;n++){
      const int col = bn*64 + wn*32 + n*16 + lr;
      #pragma unroll
      for (int r=0;r<4;r++)
        Cf[(size_t)(row+r)*N + col] = acc[m][n][r];
    }
  }
}

__device__ __forceinline__ void softmax_pack(f32x16 (&st)[2], f32x2 &lacc, bf16x8 (&pf)[4]){
  float pv[32];
  #pragma unroll
  for (int i=0;i<16;i++){
    pv[i]    = __builtin_amdgcn_exp2f(st[0][i]);
    pv[16+i] = __builtin_amdgcn_exp2f(st[1][i]);
  }
  #pragma unroll
  for (int i=0;i<8;i++){
    f32x2 a; a.x = pv[2*i];    a.y = pv[2*i+1];    lacc += a;
    f32x2 b; b.x = pv[16+2*i]; b.y = pv[16+2*i+1]; lacc += b;
  }
  #pragma unroll
  for (int t2=0; t2<2; t2++)
    #pragma unroll
    for (int e=0; e<2; e++){
      union { uint32_t u4[4]; bf16x8 v8; } pu;
      #pragma unroll
      for (int u=0; u<4; u++)
        pu.u4[u] = cvtpk(pv[t2*16+e*8+2*u], pv[t2*16+e*8+2*u+1]);
      pf[2*t2+e] = pu.v8;
    }
}

// ---------------- flash attention: 512 thr, 2 kv-halves x 4 waves, KVBLK=128 ----------------
// KVBLK=128 per half (16 barriers); in-block LDS merge: at = (O0+O1)/(l0+l1).
// LDS 133KB, 1 block/CU (grid-limited at 256 blocks).
__global__ __launch_bounds__(512, 1) void attn_kernel(
    const unsigned short* __restrict__ q, const unsigned short* __restrict__ k,
    const unsigned short* __restrict__ vt, unsigned short* __restrict__ at)
{
  __shared__ unsigned short smem[65536];  // 128KB: [half][2 dbuf][K 16KB | V 16KB]
  __shared__ float lsm[512];              // [half][256] row sums
  const int fid = blockIdx.x + 16*blockIdx.y;   // [0,256)
  const int h  = (fid&7)*2 + ((fid>>3)&1);      // XCD-grouped heads
  const int q0 = (fid>>4)*256;
  const int tid = threadIdx.x;
  const int half = tid>>8;                // 0/1: kv half
  const int ht = tid&255;                 // thread within half
  const int w = (tid>>6)&3, l = tid&63;   // wave within half, lane
  const int hi = l>>5, lo = l&31;
  const int NT = 16;                      // tiles of 128 kv per half
  const int tbase = half*NT;
  const int hbase = half*65536;           // byte offset of half's LDS region

  // ---- staging: 4 K-chunks + 4 V-chunks per thread (16B each), KVBLK=128 ----
  const unsigned short* kPtr[4]; const unsigned short* vPtr[4];
  #pragma unroll
  for (int i=0;i<4;i++){
    const int c = ht + i*256;
    const int rk = c>>3;
    const int kcol = ((c&7)*16) ^ ((rk&7)<<4);
    const int rv = c>>4;
    const int vcol = (((c&7)*16) ^ ((rv&7)<<4)) + ((c>>3)&1)*128;
    kPtr[i] = k  + (size_t)rk*HIDDEN + h*HEAD_DIM + (kcol>>1);
    vPtr[i] = vt + ((size_t)(h*HEAD_DIM + rv))*SEQ + (vcol>>1);
  }

#define STAGE(b, kOffE, vOffE) do { \
    GLD16(kPtr[0] + (kOffE), (char*)smem + hbase + (b)*32768 + (ht      )*16); \
    GLD16(kPtr[1] + (kOffE), (char*)smem + hbase + (b)*32768 + (ht+ 256 )*16); \
    GLD16(kPtr[2] + (kOffE), (char*)smem + hbase + (b)*32768 + (ht+ 512 )*16); \
    GLD16(kPtr[3] + (kOffE), (char*)smem + hbase + (b)*32768 + (ht+ 768 )*16); \
    GLD16(vPtr[0] + (vOffE), (char*)smem + hbase + (b)*32768 + 16384 + (ht      )*16); \
    GLD16(vPtr[1] + (vOffE), (char*)smem + hbase + (b)*32768 + 16384 + (ht+ 256 )*16); \
    GLD16(vPtr[2] + (vOffE), (char*)smem + hbase + (b)*32768 + 16384 + (ht+ 512 )*16); \
    GLD16(vPtr[3] + (vOffE), (char*)smem + hbase + (b)*32768 + 16384 + (ht+ 768 )*16); \
  } while(0)

  const int swz = (lo&7)<<4;
  int colo[4];
  #pragma unroll
  for (int ks=0; ks<4; ks++) colo[ks] = ((2*ks+hi)*16) ^ swz;

  bf16x8 qf0[4], qf1[4];
  {
    const unsigned short* qp = q + (size_t)(q0 + w*64 + lo)*HIDDEN + h*HEAD_DIM;
    #pragma unroll
    for (int ks=0; ks<4; ks++){
      qf0[ks] = *(const bf16x8*)(qp + ks*16 + hi*8);
      qf1[ks] = *(const bf16x8*)(qp + 32*HIDDEN + ks*16 + hi*8);
    }
  }

  f32x16 ot0[2], ot1[2];
  #pragma unroll
  for (int m2=0;m2<2;m2++)
    #pragma unroll
    for (int i=0;i<16;i++){ ot0[m2][i] = 0.f; ot1[m2][i] = 0.f; }
  f32x2 lacc0 = {0.f,0.f}, lacc1 = {0.f,0.f};

  STAGE(0, (size_t)tbase*128*HIDDEN, (size_t)tbase*128);

  for (int t = 0; t < NT; ++t) {
    __syncthreads();
    if (t+1 < NT) {
      const size_t ta = (size_t)(tbase + t + 1);
      STAGE((t+1)&1, ta*128*HIDDEN, ta*128);
    }
    const char* Kb = (const char*)smem + hbase + (t&1)*32768;
    const char* Vb = Kb + 16384;

    #pragma unroll
    for (int sub=0; sub<2; ++sub) {
      const char* Ks = Kb + sub*8192;      // 64 kv rows of 128B

      f32x16 st0[2], st1[2];
      __builtin_amdgcn_s_setprio(1);
      #pragma unroll
      for (int c=0;c<2;c++){
        #pragma unroll
        for (int i=0;i<16;i++){ st0[c][i] = 0.f; st1[c][i] = 0.f; }
        #pragma unroll
        for (int ks=0; ks<4; ks++){
          bf16x8 a = *(const bf16x8*)(Ks + (32*c+lo)*128 + colo[ks]);
          st0[c] = __builtin_amdgcn_mfma_f32_32x32x16_bf16(a, qf0[ks], st0[c], 0,0,0);
          st1[c] = __builtin_amdgcn_mfma_f32_32x32x16_bf16(a, qf1[ks], st1[c], 0,0,0);
        }
      }
      __builtin_amdgcn_s_setprio(0);

      bf16x8 pf0[4], pf1[4];
      softmax_pack(st0, lacc0, pf0);
      softmax_pack(st1, lacc1, pf1);

      __builtin_amdgcn_s_setprio(1);
      #pragma unroll
      for (int m2=0;m2<2;m2++)
        #pragma unroll
        for (int ks=0; ks<4; ks++){
          bf16x8 a = *(const bf16x8*)(Vb + (32*m2+lo)*256 + sub*128 + colo[ks]);
          ot0[m2] = __builtin_amdgcn_mfma_f32_32x32x16_bf16(a, pf0[ks], ot0[m2], 0,0,0);
          ot1[m2] = __builtin_amdgcn_mfma_f32_32x32x16_bf16(a, pf1[ks], ot1[m2], 0,0,0);
        }
      __builtin_amdgcn_s_setprio(0);
    }
  }

  // ---- per-lane row sums ----
  float ls0 = lacc0.x + lacc0.y;
  ls0 += __shfl_xor(ls0, 32);
  float ls1 = lacc1.x + lacc1.y;
  ls1 += __shfl_xor(ls1, 32);

  __syncthreads();   // all waves done reading staging LDS
  if (hi == 0){
    lsm[half*256 + w*64 + lo]      = ls0;
    lsm[half*256 + w*64 + 32 + lo] = ls1;
  }
  // ---- O fragments -> own half's LDS region ([256 q][128B], swizzled rows) ----
  #pragma unroll
  for (int m2=0;m2<2;m2++)
    #pragma unroll
    for (int f=0; f<4; f++)
      #pragma unroll
      for (int u=0; u<2; u++){
        const int d = 32*m2 + 8*f + 4*hi + 2*u;
        const uint32_t w0 = cvtpk(ot0[m2][4*f+2*u], ot0[m2][4*f+2*u+1]);
        *(uint32_t*)((char*)smem + hbase + (w*64+lo)*128 + ((d*2) ^ swz)) = w0;
        const uint32_t w1 = cvtpk(ot1[m2][4*f+2*u], ot1[m2][4*f+2*u+1]);
        *(uint32_t*)((char*)smem + hbase + (w*64+32+lo)*128 + ((d*2) ^ swz)) = w1;
      }
  __syncthreads();

  // ---- merge halves + normalize + coalesced write: 512 thr x 4 chunks ----
  {
    const int ql = tid>>1, xh = tid&1;
    const float li = 1.0f / (lsm[ql] + lsm[256 + ql]);
    #pragma unroll
    for (int i=0;i<4;i++){
      const int cb = xh*64 + i*16;
      const int off = ql*128 + (cb ^ ((ql&7)<<4));
      union { bf16x8 v; unsigned short s[8]; } a, b, o;
      a.v = *(const bf16x8*)((const char*)smem + off);
      b.v = *(const bf16x8*)((const char*)smem + 65536 + off);
      #pragma unroll
      for (int j=0;j<8;j++)
        o.s[j] = f2b((b2f(a.s[j]) + b2f(b.s[j])) * li);
      *(bf16x8*)(at + (size_t)(q0+ql)*HIDDEN + h*HEAD_DIM + (cb>>1)) = o.v;
    }
  }
#undef STAGE
}

extern "C" void kernel_launch(void* const* d_in, const int* in_sizes, int n_in,
                              void* d_out, int out_size, void* d_ws, size_t ws_size,
                              hipStream_t stream)
{
  const float* x  = (const float*)d_in[0];
  const float* rc = (const float*)d_in[1];
  const float* rs = (const float*)d_in[2];
  const float* wq = (const float*)d_in[3];
  const float* wk = (const float*)d_in[4];
  const float* wv = (const float*)d_in[5];
  const float* wo = (const float*)d_in[6];
  const float* qw = (const float*)d_in[7];
  const float* kw = (const float*)d_in[8];
  float* out = (float*)d_out;

  char* ws = (char*)d_ws;
  const size_t MB = 1024*1024;
  // layout (48MB):
  //  0.. 8: xb (A input, live through gemm_qkv)
  //  8..10 wqb  10..12 wkb  12..14 wvb (dead after qkv gemm)  14..16: wob (live)
  // 16..24 q, 24..32 k
  // 32..40: vt (written directly by gemm_qkv sel=2 epilogue)
  // 40..48: at (attention output, written directly by attn_kernel)
  unsigned short* xb  = (unsigned short*)(ws + 0);
  unsigned short* wqb = (unsigned short*)(ws + 8*MB);
  unsigned short* wkb = (unsigned short*)(ws + 10*MB);
  unsigned short* wvb = (unsigned short*)(ws + 12*MB);
  unsigned short* wob = (unsigned short*)(ws + 14*MB);
  unsigned short* qkv = (unsigned short*)(ws + 16*MB);
  unsigned short* qb = qkv;
  unsigned short* kb = qkv + (size_t)SEQ*HIDDEN;
  unsigned short* vt = (unsigned short*)(ws + 32*MB);
  unsigned short* at = (unsigned short*)(ws + 40*MB);

  convert_all<<<4096, 256, 0, stream>>>(x, wq, wk, wv, wo, xb, wqb, wkb, wvb, wob);
  gemm_qkv<<<dim3(32,24), 256, 0, stream>>>(
      xb, wqb, wkb, wvb, qb, kb, vt, rc, rs, qw, kw, SEQ, HIDDEN, HIDDEN);
  attn_kernel<<<dim3(16,16), 512, 0, stream>>>(qb, kb, vt, at);
  gemm_out<<<dim3(32,16), 256, 0, stream>>>(at, wob, out, SEQ, HIDDEN, HIDDEN);
}